// Round 4
// baseline (856.820 us; speedup 1.0000x reference)
//
#include <hip/hip_runtime.h>
#include <hip/hip_fp16.h>
#include <cstdint>
#include <cstddef>

// Problem dims (fixed by reference): B=4 S=4096 H=2048 E=64 K=2
#define HH   2048
#define MM   16384
#define NE   64
#define LN_EPS  1e-5f
#define AUX_EPS 1e-9f

typedef __attribute__((ext_vector_type(8))) _Float16 f16x8;
typedef __attribute__((ext_vector_type(4))) _Float16 f16x4;
typedef __attribute__((ext_vector_type(4))) float    f32x4;

__device__ __forceinline__ void gload_lds16(const void* g, void* l) {
    __builtin_amdgcn_global_load_lds(
        (const __attribute__((address_space(1))) unsigned int*)g,
        (__attribute__((address_space(3))) unsigned int*)l,
        16, 0, 0);
}

// XOR-swizzle for 256B-row LDS tiles: involution (target bits 4-6 disjoint
// from source bits 8-10), preserves 8B/16B granules.
__device__ __forceinline__ uint32_t swz256(uint32_t x) {
    return x ^ (((x >> 8) & 7u) << 4);
}

// ---------------------------------------------------------------------------
// Kernel 1: W1 [K][N] f32 -> Wh [N][K] fp16 (hi), Wl [N][K] fp16 (lo * 2^10)
// (round-2 verbatim, proven)
// ---------------------------------------------------------------------------
__global__ __launch_bounds__(256) void k_tw1(const float* __restrict__ W1,
                                             _Float16* __restrict__ whp,
                                             _Float16* __restrict__ wlp) {
    __shared__ float tile[32][33];
    int tx = threadIdx.x & 31;
    int ty = threadIdx.x >> 5;          // 0..7
    int bx = blockIdx.x & 63;           // n-tile
    int by = blockIdx.x >> 6;           // k-tile
#pragma unroll
    for (int i = 0; i < 4; ++i) {
        int k = by * 32 + ty + i * 8;
        tile[ty + i * 8][tx] = W1[(size_t)k * HH + bx * 32 + tx];
    }
    __syncthreads();
#pragma unroll
    for (int i = 0; i < 4; ++i) {
        int n = bx * 32 + ty + i * 8;
        float w = tile[tx][ty + i * 8];
        _Float16 hi = (_Float16)w;
        _Float16 lo = (_Float16)((w - (float)hi) * 1024.0f);
        whp[(size_t)n * HH + by * 32 + tx] = hi;
        wlp[(size_t)n * HH + by * 32 + tx] = lo;
    }
}

// ---------------------------------------------------------------------------
// Kernel 2: W2 [K][64] f32 -> w2q [64][2048 quads] fp16 {hi, hi, lo*2^10, 0}
// ---------------------------------------------------------------------------
__global__ __launch_bounds__(256) void k_w2q(const float* __restrict__ W2,
                                             _Float16* __restrict__ w2q) {
    int e = blockIdx.x;                 // 64
    int t = threadIdx.x;                // 256
#pragma unroll
    for (int j = 0; j < 8; ++j) {
        int c = t * 8 + j;              // 0..2047
        float w = W2[(size_t)c * NE + e];
        _Float16 hi = (_Float16)w;
        _Float16 lo = (_Float16)((w - (float)hi) * 1024.0f);
        f16x4 q = {hi, hi, lo, (_Float16)0.0f};
        *(f16x4*)&w2q[(size_t)e * 8192 + (size_t)c * 4] = q;
    }
}

// ---------------------------------------------------------------------------
// Kernel 3: LayerNorm -> xh (fp16 hi), xl (fp16 lo)  (round-2 verbatim)
// ---------------------------------------------------------------------------
__global__ __launch_bounds__(256) void k_ln(const float* __restrict__ x,
                                            const float* __restrict__ gamma,
                                            const float* __restrict__ beta,
                                            _Float16* __restrict__ xh,
                                            _Float16* __restrict__ xl) {
    int row = blockIdx.x;
    int t = threadIdx.x;
    const float4* xr = (const float4*)(x + (size_t)row * HH);
    float4 v0 = xr[t];
    float4 v1 = xr[t + 256];
    float s  = v0.x + v0.y + v0.z + v0.w + v1.x + v1.y + v1.z + v1.w;
    float sq = v0.x*v0.x + v0.y*v0.y + v0.z*v0.z + v0.w*v0.w
             + v1.x*v1.x + v1.y*v1.y + v1.z*v1.z + v1.w*v1.w;
#pragma unroll
    for (int m = 1; m < 64; m <<= 1) { s += __shfl_xor(s, m); sq += __shfl_xor(sq, m); }
    __shared__ float red[8];
    int wv = t >> 6;
    if ((t & 63) == 0) { red[wv] = s; red[wv + 4] = sq; }
    __syncthreads();
    s  = red[0] + red[1] + red[2] + red[3];
    sq = red[4] + red[5] + red[6] + red[7];
    float mu  = s * (1.0f / HH);
    float var = sq * (1.0f / HH) - mu * mu;
    float rr  = rsqrtf(var + LN_EPS);

    const float4* gr = (const float4*)gamma;
    const float4* br = (const float4*)beta;
#pragma unroll
    for (int p = 0; p < 2; ++p) {
        int idx = t + p * 256;
        float4 v = (p == 0) ? v0 : v1;
        float4 g = gr[idx];
        float4 b = br[idx];
        float f[4];
        f[0] = (v.x - mu) * rr * g.x + b.x;
        f[1] = (v.y - mu) * rr * g.y + b.y;
        f[2] = (v.z - mu) * rr * g.z + b.z;
        f[3] = (v.w - mu) * rr * g.w + b.w;
        f16x4 oh, ol;
#pragma unroll
        for (int j = 0; j < 4; ++j) {
            _Float16 hi = (_Float16)f[j];
            oh[j] = hi;
            ol[j] = (_Float16)(f[j] - (float)hi);
        }
        *(f16x4*)&xh[(size_t)row * HH + idx * 4] = oh;
        *(f16x4*)&xl[(size_t)row * HH + idx * 4] = ol;
    }
}

// ---------------------------------------------------------------------------
// Kernel 4: GEMM1 (round-2 main loop verbatim: 128x128 tile, BK=32, 4 waves,
// fp16 3-pass split) + NEW fused epilogue: h -> fp16 quads in LDS -> MFMA vs
// W2 quads -> partial logits part[bn][row][64] (deterministic, no atomics).
// ---------------------------------------------------------------------------
__global__ __launch_bounds__(256) void k_gemm(const _Float16* __restrict__ Ah_g,
                                              const _Float16* __restrict__ Al_g,
                                              const _Float16* __restrict__ Bh_g,
                                              const _Float16* __restrict__ Bl_g,
                                              const _Float16* __restrict__ w2q,
                                              const float* __restrict__ b1,
                                              float* __restrict__ part) {
    __shared__ __align__(16) char lds[49152];
    _Float16* Ah = (_Float16*)(lds);            // 8KB  [128][32]
    _Float16* Al = (_Float16*)(lds + 8192);     // 8KB
    _Float16* Bh = (_Float16*)(lds + 16384);    // 8KB
    _Float16* Bl = (_Float16*)(lds + 24576);    // 8KB

    // XCD-aware bijective swizzle (2048 % 8 == 0); bn-fastest so 16 blocks
    // sharing one XCD reuse the same 1MB A-slice from that XCD's L2.
    int wg = (blockIdx.x & 7) * 256 + (blockIdx.x >> 3);
    int bm = wg >> 4;               // 0..127
    int bn = wg & 15;               // 0..15
    int t = threadIdx.x;
    int lane = t & 63;
    int w = t >> 6;
    int wr = w >> 1, wc = w & 1;    // 2x2 wave grid, 64x64 out each

    f32x4 acc[4][4];
#pragma unroll
    for (int m = 0; m < 4; ++m)
#pragma unroll
        for (int n = 0; n < 4; ++n)
            acc[m][n] = (f32x4){0.f, 0.f, 0.f, 0.f};

    const char* pAh = (const char*)Ah_g;
    const char* pAl = (const char*)Al_g;
    const char* pBh = (const char*)Bh_g;
    const char* pBl = (const char*)Bl_g;
    int srow = t >> 2;              // 0..63
    int scolb = (t & 3) * 16;       // byte offset in 64B k-chunk
    size_t a_row = (size_t)bm * 128 + srow;
    size_t b_row = (size_t)bn * 128 + srow;
    int r16 = lane & 15, ko = lane >> 4;

    for (int kt = 0; kt < HH / 32; ++kt) {
        __syncthreads();
        size_t kb = (size_t)kt * 64 + scolb;    // 32 fp16 = 64 B per row-chunk
        gload_lds16(pAh + (a_row     ) * (HH*2) + kb, lds + t * 16);
        gload_lds16(pAh + (a_row + 64) * (HH*2) + kb, lds + 4096 + t * 16);
        gload_lds16(pAl + (a_row     ) * (HH*2) + kb, lds + 8192 + t * 16);
        gload_lds16(pAl + (a_row + 64) * (HH*2) + kb, lds + 8192 + 4096 + t * 16);
        gload_lds16(pBh + (b_row     ) * (HH*2) + kb, lds + 16384 + t * 16);
        gload_lds16(pBh + (b_row + 64) * (HH*2) + kb, lds + 16384 + 4096 + t * 16);
        gload_lds16(pBl + (b_row     ) * (HH*2) + kb, lds + 24576 + t * 16);
        gload_lds16(pBl + (b_row + 64) * (HH*2) + kb, lds + 24576 + 4096 + t * 16);
        __syncthreads();

        f16x8 fah[4], fal[4], fbh[4], fbl[4];
#pragma unroll
        for (int m = 0; m < 4; ++m) {
            int ro = (wr * 64 + m * 16 + r16) * 32 + ko * 8;
            fah[m] = *(const f16x8*)&Ah[ro];
            fal[m] = *(const f16x8*)&Al[ro];
        }
#pragma unroll
        for (int n = 0; n < 4; ++n) {
            int ro = (wc * 64 + n * 16 + r16) * 32 + ko * 8;
            fbh[n] = *(const f16x8*)&Bh[ro];
            fbl[n] = *(const f16x8*)&Bl[ro];
        }
#pragma unroll
        for (int m = 0; m < 4; ++m) {
            f16x8 fas = fah[m] * (_Float16)0.0009765625f;   // xh * 2^-10 (exact)
#pragma unroll
            for (int n = 0; n < 4; ++n) {
                acc[m][n] = __builtin_amdgcn_mfma_f32_16x16x32_f16(fah[m], fbh[n], acc[m][n], 0, 0, 0);
                acc[m][n] = __builtin_amdgcn_mfma_f32_16x16x32_f16(fal[m], fbh[n], acc[m][n], 0, 0, 0);
                acc[m][n] = __builtin_amdgcn_mfma_f32_16x16x32_f16(fas,    fbl[n], acc[m][n], 0, 0, 0);
            }
        }
    }

    // ---------------- NEW epilogue: logits partials via MFMA -----------------
    __syncthreads();                     // main-loop LDS reads done, safe to reuse
    char* A2 = lds;                      // 32KB: [128 rows][32 cols x 8B quads]
    char* B2 = lds + 32768;              // 16KB: [64 experts][32 cols x 8B quads]

    float bv[4];
#pragma unroll
    for (int n = 0; n < 4; ++n)
        bv[n] = b1[bn * 128 + wc * 64 + n * 16 + r16];

    f32x4 acc2[2][4];
#pragma unroll
    for (int mf = 0; mf < 2; ++mf)
#pragma unroll
        for (int ef = 0; ef < 4; ++ef)
            acc2[mf][ef] = (f32x4){0.f, 0.f, 0.f, 0.f};

    int hi4 = lane >> 4;
    int ko16 = ko * 16;                  // byte offset of the lane's k-group

    for (int c = 0; c < 4; ++c) {        // 4 chunks of 32 h-cols
        // stage B2 chunk: 64 experts x 256B; thread covers 64B
        {
            const char* src = (const char*)w2q + (size_t)(t >> 2) * 16384
                            + (size_t)bn * 1024 + (size_t)c * 256 + (t & 3) * 64;
            uint32_t db = (uint32_t)(t >> 2) * 256 + (t & 3) * 64;
#pragma unroll
            for (int j = 0; j < 4; ++j)
                *(f16x8*)(B2 + swz256(db + j * 16)) = *(const f16x8*)(src + j * 16);
        }
        // owner waves (wc == c>>1) write h quads {hh, hl, hh*2^-10, 0}
        if (wc == (c >> 1)) {
            int np = (c & 1) * 2;
#pragma unroll
            for (int nn = 0; nn < 2; ++nn) {
                int n = np + nn;
#pragma unroll
                for (int m = 0; m < 4; ++m)
#pragma unroll
                    for (int i = 0; i < 4; ++i) {
                        float h = acc[m][n][i] + bv[n];
                        h = fmaxf(h, 0.f);
                        _Float16 hh = (_Float16)h;
                        float hhf = (float)hh;
                        _Float16 hl = (_Float16)(h - hhf);
                        _Float16 hs = (_Float16)(hhf * 0.0009765625f);
                        int row = wr * 64 + m * 16 + hi4 * 4 + i;
                        int cc = nn * 16 + r16;            // 0..31 within chunk
                        f16x4 q = {hh, hl, hs, (_Float16)0.0f};
                        *(f16x4*)(A2 + swz256((uint32_t)row * 256 + cc * 8)) = q;
                    }
            }
        }
        __syncthreads();
        // logits MFMA: wave strip = rows w*32..+32, all 64 experts, K=128 vk
#pragma unroll
        for (int kk = 0; kk < 4; ++kk) {
            f16x8 bfr[4];
#pragma unroll
            for (int ef = 0; ef < 4; ++ef)
                bfr[ef] = *(const f16x8*)(B2 +
                    swz256((uint32_t)(ef * 16 + r16) * 256 + kk * 64 + ko16));
#pragma unroll
            for (int mf = 0; mf < 2; ++mf) {
                f16x8 afr = *(const f16x8*)(A2 +
                    swz256((uint32_t)(w * 32 + mf * 16 + r16) * 256 + kk * 64 + ko16));
#pragma unroll
                for (int ef = 0; ef < 4; ++ef)
                    acc2[mf][ef] = __builtin_amdgcn_mfma_f32_16x16x32_f16(
                        afr, bfr[ef], acc2[mf][ef], 0, 0, 0);
            }
        }
        __syncthreads();
    }

    // write partial logits: part[bn][grow][e]
#pragma unroll
    for (int mf = 0; mf < 2; ++mf)
#pragma unroll
        for (int i = 0; i < 4; ++i) {
            int grow = bm * 128 + w * 32 + mf * 16 + hi4 * 4 + i;
            float* dst = part + ((size_t)bn * MM + grow) * NE;
#pragma unroll
            for (int ef = 0; ef < 4; ++ef)
                dst[ef * 16 + r16] = acc2[mf][ef][i];
        }
}

// ---------------------------------------------------------------------------
// Kernel 5: reduce 16 partial slices -> logits [MM][64]
// ---------------------------------------------------------------------------
__global__ __launch_bounds__(256) void k_red(const float* __restrict__ part,
                                             float* __restrict__ lg) {
    int i = blockIdx.x * 256 + threadIdx.x;     // 0 .. 1048575
    float s = 0.f;
#pragma unroll
    for (int sl = 0; sl < 16; ++sl)
        s += part[(size_t)sl * (MM * NE) + i];
    lg[i] = s;
}

// ---------------------------------------------------------------------------
// Kernel 6: per-row softmax over 64, top-2 (jax ties: lower index first),
// renorm, outputs, expert-prob sums.  (round-2 verbatim, proven)
// ---------------------------------------------------------------------------
__global__ __launch_bounds__(256) void k_final(const float* __restrict__ logits,
                                               const float* __restrict__ b2,
                                               float* __restrict__ out,
                                               float* __restrict__ sums) {
    int r = blockIdx.x * 256 + threadIdx.x;
    const float* lr = logits + (size_t)r * NE;
    float l[NE];
#pragma unroll
    for (int e = 0; e < NE; e += 4) {
        float4 v = *(const float4*)&lr[e];
        float4 b = *(const float4*)&b2[e];
        l[e]     = v.x + b.x;
        l[e + 1] = v.y + b.y;
        l[e + 2] = v.z + b.z;
        l[e + 3] = v.w + b.w;
    }
    float m1 = -1e30f, m2 = -1e30f;
    int i1 = 0, i2 = 0;
#pragma unroll
    for (int e = 0; e < NE; ++e) {
        if (l[e] > m1)      { m2 = m1; i2 = i1; m1 = l[e]; i1 = e; }
        else if (l[e] > m2) { m2 = l[e]; i2 = e; }
    }
    float ev[NE];
    float Z = 0.f;
#pragma unroll
    for (int e = 0; e < NE; ++e) { ev[e] = expf(l[e] - m1); Z += ev[e]; }

    float eb = expf(m2 - m1);
    float pa = 1.0f / (1.0f + eb);
    float pb = eb * pa;

    out[(size_t)r * 2 + 0] = (float)i1;
    out[(size_t)r * 2 + 1] = (float)i2;
    out[(size_t)2 * MM + r * 2 + 0] = pa;
    out[(size_t)2 * MM + r * 2 + 1] = pb;

    float invZ = 1.0f / Z;
    __shared__ float red[4][NE];
    int lane = threadIdx.x & 63, wv = threadIdx.x >> 6;
#pragma unroll
    for (int e = 0; e < NE; ++e) {
        float q = ev[e] * invZ;
#pragma unroll
        for (int sh = 1; sh < 64; sh <<= 1) q += __shfl_xor(q, sh);
        if (lane == e) red[wv][e] = q;
    }
    __syncthreads();
    if (threadIdx.x < NE) {
        float tot = red[0][threadIdx.x] + red[1][threadIdx.x]
                  + red[2][threadIdx.x] + red[3][threadIdx.x];
        atomicAdd(&sums[threadIdx.x], tot);
    }
}

// ---------------------------------------------------------------------------
// Kernel 7: aux loss
// ---------------------------------------------------------------------------
__global__ void k_aux(const float* __restrict__ sums, float* __restrict__ out) {
    if (threadIdx.x == 0) {
        float loss = 0.f;
        for (int e = 0; e < NE; ++e) {
            float p = sums[e] * (1.0f / MM);
            loss += p * logf(p * (float)NE + AUX_EPS);
        }
        out[(size_t)4 * MM] = loss;   // index 65536
    }
}

// ---------------------------------------------------------------------------
extern "C" void kernel_launch(void* const* d_in, const int* in_sizes, int n_in,
                              void* d_out, int out_size, void* d_ws, size_t ws_size,
                              hipStream_t stream) {
    const float* x     = (const float*)d_in[0];
    const float* W1    = (const float*)d_in[1];
    const float* b1    = (const float*)d_in[2];
    const float* W2    = (const float*)d_in[3];
    const float* b2    = (const float*)d_in[4];
    const float* gamma = (const float*)d_in[5];
    const float* beta  = (const float*)d_in[6];
    float* out = (float*)d_out;

    char* ws = (char*)d_ws;
    _Float16* xh  = (_Float16*)(ws);                        //  67,108,864 B
    _Float16* xl  = (_Float16*)(ws + 67108864);             //  67,108,864 B
    _Float16* whp = (_Float16*)(ws + 134217728);            //   8,388,608 B
    _Float16* wlp = (_Float16*)(ws + 142606336);            //   8,388,608 B
    _Float16* w2q = (_Float16*)(ws + 150994944);            //   1,048,576 B
    float*    part = (float*)  (ws + 152043520);            //  67,108,864 B
    float*    lg   = (float*)  (ws + 219152384);            //   4,194,304 B
    float*    sums = (float*)  (ws + 223346688);            //         256 B

    hipMemsetAsync(sums, 0, NE * sizeof(float), stream);
    k_tw1  <<<4096,    256, 0, stream>>>(W1, whp, wlp);
    k_w2q  <<<64,      256, 0, stream>>>(W2, w2q);
    k_ln   <<<MM,      256, 0, stream>>>(x, gamma, beta, xh, xl);
    k_gemm <<<2048,    256, 0, stream>>>(xh, xl, whp, wlp, w2q, b1, part);
    k_red  <<<4096,    256, 0, stream>>>(part, lg);
    k_final<<<MM/256,  256, 0, stream>>>(lg, b2, out, sums);
    k_aux  <<<1,       64,  0, stream>>>(sums, out);
}

// Round 5
// 513.427 us; speedup vs baseline: 1.6688x; 1.6688x over previous
//
#include <hip/hip_runtime.h>
#include <hip/hip_fp16.h>
#include <cstdint>
#include <cstddef>

// Problem dims (fixed by reference): B=4 S=4096 H=2048 E=64 K=2
#define HH   2048
#define MM   16384
#define NE   64
#define LN_EPS  1e-5f
#define AUX_EPS 1e-9f

typedef __attribute__((ext_vector_type(8))) _Float16 f16x8;
typedef __attribute__((ext_vector_type(4))) _Float16 f16x4;
typedef __attribute__((ext_vector_type(4))) float    f32x4;

__device__ __forceinline__ void gload_lds16(const void* g, void* l) {
    __builtin_amdgcn_global_load_lds(
        (const __attribute__((address_space(1))) unsigned int*)g,
        (__attribute__((address_space(3))) unsigned int*)l,
        16, 0, 0);
}

// XOR-swizzle for 128B-row LDS tiles: byte bits 4-6 ^= row bits (byte 7-9).
// Involution (target bits disjoint from source bits); preserves 8B/16B granules.
__device__ __forceinline__ uint32_t swz128(uint32_t x) {
    return x ^ (((x >> 7) & 7u) << 4);
}

// ---------------------------------------------------------------------------
// Kernel 1: W1 [K][N] f32 -> Wh [N][K] fp16 (hi), Wl [N][K] fp16 (lo * 2^10)
// ---------------------------------------------------------------------------
__global__ __launch_bounds__(256) void k_tw1(const float* __restrict__ W1,
                                             _Float16* __restrict__ whp,
                                             _Float16* __restrict__ wlp) {
    __shared__ float tile[32][33];
    int tx = threadIdx.x & 31;
    int ty = threadIdx.x >> 5;          // 0..7
    int bx = blockIdx.x & 63;           // n-tile
    int by = blockIdx.x >> 6;           // k-tile
#pragma unroll
    for (int i = 0; i < 4; ++i) {
        int k = by * 32 + ty + i * 8;
        tile[ty + i * 8][tx] = W1[(size_t)k * HH + bx * 32 + tx];
    }
    __syncthreads();
#pragma unroll
    for (int i = 0; i < 4; ++i) {
        int n = bx * 32 + ty + i * 8;
        float w = tile[tx][ty + i * 8];
        _Float16 hi = (_Float16)w;
        _Float16 lo = (_Float16)((w - (float)hi) * 1024.0f);
        whp[(size_t)n * HH + by * 32 + tx] = hi;
        wlp[(size_t)n * HH + by * 32 + tx] = lo;
    }
}

// ---------------------------------------------------------------------------
// Kernel 2: W2 [K][64] f32 -> w2q [64][2048 quads] fp16 {hi, hi, lo*2^10, 0}
// ---------------------------------------------------------------------------
__global__ __launch_bounds__(256) void k_w2q(const float* __restrict__ W2,
                                             _Float16* __restrict__ w2q) {
    int e = blockIdx.x;                 // 64
    int t = threadIdx.x;                // 256
#pragma unroll
    for (int j = 0; j < 8; ++j) {
        int c = t * 8 + j;              // 0..2047
        float w = W2[(size_t)c * NE + e];
        _Float16 hi = (_Float16)w;
        _Float16 lo = (_Float16)((w - (float)hi) * 1024.0f);
        f16x4 q = {hi, hi, lo, (_Float16)0.0f};
        *(f16x4*)&w2q[(size_t)e * 8192 + (size_t)c * 4] = q;
    }
}

// ---------------------------------------------------------------------------
// Kernel 3: LayerNorm -> xh (fp16 hi), xl (fp16 lo)
// ---------------------------------------------------------------------------
__global__ __launch_bounds__(256) void k_ln(const float* __restrict__ x,
                                            const float* __restrict__ gamma,
                                            const float* __restrict__ beta,
                                            _Float16* __restrict__ xh,
                                            _Float16* __restrict__ xl) {
    int row = blockIdx.x;
    int t = threadIdx.x;
    const float4* xr = (const float4*)(x + (size_t)row * HH);
    float4 v0 = xr[t];
    float4 v1 = xr[t + 256];
    float s  = v0.x + v0.y + v0.z + v0.w + v1.x + v1.y + v1.z + v1.w;
    float sq = v0.x*v0.x + v0.y*v0.y + v0.z*v0.z + v0.w*v0.w
             + v1.x*v1.x + v1.y*v1.y + v1.z*v1.z + v1.w*v1.w;
#pragma unroll
    for (int m = 1; m < 64; m <<= 1) { s += __shfl_xor(s, m); sq += __shfl_xor(sq, m); }
    __shared__ float red[8];
    int wv = t >> 6;
    if ((t & 63) == 0) { red[wv] = s; red[wv + 4] = sq; }
    __syncthreads();
    s  = red[0] + red[1] + red[2] + red[3];
    sq = red[4] + red[5] + red[6] + red[7];
    float mu  = s * (1.0f / HH);
    float var = sq * (1.0f / HH) - mu * mu;
    float rr  = rsqrtf(var + LN_EPS);

    const float4* gr = (const float4*)gamma;
    const float4* br = (const float4*)beta;
#pragma unroll
    for (int p = 0; p < 2; ++p) {
        int idx = t + p * 256;
        float4 v = (p == 0) ? v0 : v1;
        float4 g = gr[idx];
        float4 b = br[idx];
        float f[4];
        f[0] = (v.x - mu) * rr * g.x + b.x;
        f[1] = (v.y - mu) * rr * g.y + b.y;
        f[2] = (v.z - mu) * rr * g.z + b.z;
        f[3] = (v.w - mu) * rr * g.w + b.w;
        f16x4 oh, ol;
#pragma unroll
        for (int j = 0; j < 4; ++j) {
            _Float16 hi = (_Float16)f[j];
            oh[j] = hi;
            ol[j] = (_Float16)(f[j] - (float)hi);
        }
        *(f16x4*)&xh[(size_t)row * HH + idx * 4] = oh;
        *(f16x4*)&xl[(size_t)row * HH + idx * 4] = ol;
    }
}

// ---------------------------------------------------------------------------
// Kernel 4: GEMM1 (round-2 main loop verbatim) + fused logits epilogue
// (proven round-4, re-chunked to 16 cols so LDS stays 32KB).
// __launch_bounds__(256,2): keep VGPR+AGPR <= 256 -> 2 blocks/CU resident.
// ---------------------------------------------------------------------------
__global__ __launch_bounds__(256, 2) void k_gemm(const _Float16* __restrict__ Ah_g,
                                                 const _Float16* __restrict__ Al_g,
                                                 const _Float16* __restrict__ Bh_g,
                                                 const _Float16* __restrict__ Bl_g,
                                                 const _Float16* __restrict__ w2q,
                                                 const float* __restrict__ b1,
                                                 float* __restrict__ part) {
    __shared__ __align__(16) char lds[32768];
    _Float16* Ah = (_Float16*)(lds);            // 8KB  [128][32]
    _Float16* Al = (_Float16*)(lds + 8192);     // 8KB
    _Float16* Bh = (_Float16*)(lds + 16384);    // 8KB
    _Float16* Bl = (_Float16*)(lds + 24576);    // 8KB

    int bm = blockIdx.x >> 4;       // 0..127  (natural order, round-2 proven)
    int bn = blockIdx.x & 15;       // 0..15
    int t = threadIdx.x;
    int lane = t & 63;
    int w = t >> 6;
    int wr = w >> 1, wc = w & 1;    // 2x2 wave grid, 64x64 out each

    f32x4 acc[4][4];
#pragma unroll
    for (int m = 0; m < 4; ++m)
#pragma unroll
        for (int n = 0; n < 4; ++n)
            acc[m][n] = (f32x4){0.f, 0.f, 0.f, 0.f};

    const char* pAh = (const char*)Ah_g;
    const char* pAl = (const char*)Al_g;
    const char* pBh = (const char*)Bh_g;
    const char* pBl = (const char*)Bl_g;
    int srow = t >> 2;              // 0..63
    int scolb = (t & 3) * 16;       // byte offset in 64B k-chunk
    size_t a_row = (size_t)bm * 128 + srow;
    size_t b_row = (size_t)bn * 128 + srow;
    int r16 = lane & 15, ko = lane >> 4;

    for (int kt = 0; kt < HH / 32; ++kt) {
        __syncthreads();
        size_t kb = (size_t)kt * 64 + scolb;    // 32 fp16 = 64 B per row-chunk
        gload_lds16(pAh + (a_row     ) * (HH*2) + kb, lds + t * 16);
        gload_lds16(pAh + (a_row + 64) * (HH*2) + kb, lds + 4096 + t * 16);
        gload_lds16(pAl + (a_row     ) * (HH*2) + kb, lds + 8192 + t * 16);
        gload_lds16(pAl + (a_row + 64) * (HH*2) + kb, lds + 8192 + 4096 + t * 16);
        gload_lds16(pBh + (b_row     ) * (HH*2) + kb, lds + 16384 + t * 16);
        gload_lds16(pBh + (b_row + 64) * (HH*2) + kb, lds + 16384 + 4096 + t * 16);
        gload_lds16(pBl + (b_row     ) * (HH*2) + kb, lds + 24576 + t * 16);
        gload_lds16(pBl + (b_row + 64) * (HH*2) + kb, lds + 24576 + 4096 + t * 16);
        __syncthreads();

        f16x8 fah[4], fal[4], fbh[4], fbl[4];
#pragma unroll
        for (int m = 0; m < 4; ++m) {
            int ro = (wr * 64 + m * 16 + r16) * 32 + ko * 8;
            fah[m] = *(const f16x8*)&Ah[ro];
            fal[m] = *(const f16x8*)&Al[ro];
        }
#pragma unroll
        for (int n = 0; n < 4; ++n) {
            int ro = (wc * 64 + n * 16 + r16) * 32 + ko * 8;
            fbh[n] = *(const f16x8*)&Bh[ro];
            fbl[n] = *(const f16x8*)&Bl[ro];
        }
#pragma unroll
        for (int m = 0; m < 4; ++m) {
            f16x8 fas = fah[m] * (_Float16)0.0009765625f;   // xh * 2^-10 (exact)
#pragma unroll
            for (int n = 0; n < 4; ++n) {
                acc[m][n] = __builtin_amdgcn_mfma_f32_16x16x32_f16(fah[m], fbh[n], acc[m][n], 0, 0, 0);
                acc[m][n] = __builtin_amdgcn_mfma_f32_16x16x32_f16(fal[m], fbh[n], acc[m][n], 0, 0, 0);
                acc[m][n] = __builtin_amdgcn_mfma_f32_16x16x32_f16(fas,    fbl[n], acc[m][n], 0, 0, 0);
            }
        }
    }

    // ---------------- fused epilogue: logits partials via MFMA ---------------
    __syncthreads();                     // main-loop LDS reads done, safe to reuse
    char* A2 = lds;                      // 16KB: [128 rows][16 quads x 8B], swz128
    char* B2 = lds + 16384;              // 8KB:  [64 experts][16 quads x 8B], swz128

    float bv[4];
#pragma unroll
    for (int n = 0; n < 4; ++n)
        bv[n] = b1[bn * 128 + wc * 64 + n * 16 + r16];

    f32x4 acc2[2][4];
#pragma unroll
    for (int mf = 0; mf < 2; ++mf)
#pragma unroll
        for (int ef = 0; ef < 4; ++ef)
            acc2[mf][ef] = (f32x4){0.f, 0.f, 0.f, 0.f};

    int hi4 = lane >> 4;
    int ko16 = ko * 16;                  // byte offset of the lane's k-group

    for (int c = 0; c < 8; ++c) {        // 8 chunks of 16 h-cols
        // stage B2 chunk: 64 experts x 128B; thread covers 32B
        {
            const char* src = (const char*)w2q + (size_t)(t >> 2) * 16384
                            + (size_t)bn * 1024 + (size_t)c * 128 + (t & 3) * 32;
            uint32_t db = (uint32_t)(t >> 2) * 128 + (t & 3) * 32;
            *(f16x8*)(B2 + swz128(db))      = *(const f16x8*)(src);
            *(f16x8*)(B2 + swz128(db + 16)) = *(const f16x8*)(src + 16);
        }
        // owner waves (wc == c>>2) write h quads {hh, hl, hh*2^-10, 0}
        if (wc == (c >> 2)) {
            int n = c & 3;
#pragma unroll
            for (int m = 0; m < 4; ++m)
#pragma unroll
                for (int i = 0; i < 4; ++i) {
                    float h = acc[m][n][i] + bv[n];
                    h = fmaxf(h, 0.f);
                    _Float16 hh = (_Float16)h;
                    float hhf = (float)hh;
                    _Float16 hl = (_Float16)(h - hhf);
                    _Float16 hs = (_Float16)(hhf * 0.0009765625f);
                    int row = wr * 64 + m * 16 + hi4 * 4 + i;
                    f16x4 q = {hh, hl, hs, (_Float16)0.0f};
                    *(f16x4*)(A2 + swz128((uint32_t)row * 128 + r16 * 8)) = q;
                }
        }
        __syncthreads();
        // logits MFMA: wave strip = rows w*32..+32, all 64 experts, 2 K-steps
#pragma unroll
        for (int kk = 0; kk < 2; ++kk) {
            f16x8 bfr[4];
#pragma unroll
            for (int ef = 0; ef < 4; ++ef)
                bfr[ef] = *(const f16x8*)(B2 +
                    swz128((uint32_t)(ef * 16 + r16) * 128 + kk * 64 + ko16));
#pragma unroll
            for (int mf = 0; mf < 2; ++mf) {
                f16x8 afr = *(const f16x8*)(A2 +
                    swz128((uint32_t)(w * 32 + mf * 16 + r16) * 128 + kk * 64 + ko16));
#pragma unroll
                for (int ef = 0; ef < 4; ++ef)
                    acc2[mf][ef] = __builtin_amdgcn_mfma_f32_16x16x32_f16(
                        afr, bfr[ef], acc2[mf][ef], 0, 0, 0);
            }
        }
        __syncthreads();
    }

    // write partial logits: part[bn][grow][e]
#pragma unroll
    for (int mf = 0; mf < 2; ++mf)
#pragma unroll
        for (int i = 0; i < 4; ++i) {
            int grow = bm * 128 + w * 32 + mf * 16 + hi4 * 4 + i;
            float* dst = part + ((size_t)bn * MM + grow) * NE;
#pragma unroll
            for (int ef = 0; ef < 4; ++ef)
                dst[ef * 16 + r16] = acc2[mf][ef][i];
        }
}

// ---------------------------------------------------------------------------
// Kernel 5: reduce 16 partial slices -> logits [MM][64]
// ---------------------------------------------------------------------------
__global__ __launch_bounds__(256) void k_red(const float* __restrict__ part,
                                             float* __restrict__ lg) {
    int i = blockIdx.x * 256 + threadIdx.x;     // 0 .. 1048575
    float s = 0.f;
#pragma unroll
    for (int sl = 0; sl < 16; ++sl)
        s += part[(size_t)sl * (MM * NE) + i];
    lg[i] = s;
}

// ---------------------------------------------------------------------------
// Kernel 6: per-row softmax over 64, top-2 (jax ties: lower index first),
// renorm, outputs, expert-prob sums.
// ---------------------------------------------------------------------------
__global__ __launch_bounds__(256) void k_final(const float* __restrict__ logits,
                                               const float* __restrict__ b2,
                                               float* __restrict__ out,
                                               float* __restrict__ sums) {
    int r = blockIdx.x * 256 + threadIdx.x;
    const float* lr = logits + (size_t)r * NE;
    float l[NE];
#pragma unroll
    for (int e = 0; e < NE; e += 4) {
        float4 v = *(const float4*)&lr[e];
        float4 b = *(const float4*)&b2[e];
        l[e]     = v.x + b.x;
        l[e + 1] = v.y + b.y;
        l[e + 2] = v.z + b.z;
        l[e + 3] = v.w + b.w;
    }
    float m1 = -1e30f, m2 = -1e30f;
    int i1 = 0, i2 = 0;
#pragma unroll
    for (int e = 0; e < NE; ++e) {
        if (l[e] > m1)      { m2 = m1; i2 = i1; m1 = l[e]; i1 = e; }
        else if (l[e] > m2) { m2 = l[e]; i2 = e; }
    }
    float ev[NE];
    float Z = 0.f;
#pragma unroll
    for (int e = 0; e < NE; ++e) { ev[e] = expf(l[e] - m1); Z += ev[e]; }

    float eb = expf(m2 - m1);
    float pa = 1.0f / (1.0f + eb);
    float pb = eb * pa;

    out[(size_t)r * 2 + 0] = (float)i1;
    out[(size_t)r * 2 + 1] = (float)i2;
    out[(size_t)2 * MM + r * 2 + 0] = pa;
    out[(size_t)2 * MM + r * 2 + 1] = pb;

    float invZ = 1.0f / Z;
    __shared__ float red[4][NE];
    int lane = threadIdx.x & 63, wv = threadIdx.x >> 6;
#pragma unroll
    for (int e = 0; e < NE; ++e) {
        float q = ev[e] * invZ;
#pragma unroll
        for (int sh = 1; sh < 64; sh <<= 1) q += __shfl_xor(q, sh);
        if (lane == e) red[wv][e] = q;
    }
    __syncthreads();
    if (threadIdx.x < NE) {
        float tot = red[0][threadIdx.x] + red[1][threadIdx.x]
                  + red[2][threadIdx.x] + red[3][threadIdx.x];
        atomicAdd(&sums[threadIdx.x], tot);
    }
}

// ---------------------------------------------------------------------------
// Kernel 7: aux loss
// ---------------------------------------------------------------------------
__global__ void k_aux(const float* __restrict__ sums, float* __restrict__ out) {
    if (threadIdx.x == 0) {
        float loss = 0.f;
        for (int e = 0; e < NE; ++e) {
            float p = sums[e] * (1.0f / MM);
            loss += p * logf(p * (float)NE + AUX_EPS);
        }
        out[(size_t)4 * MM] = loss;   // index 65536
    }
}

// ---------------------------------------------------------------------------
extern "C" void kernel_launch(void* const* d_in, const int* in_sizes, int n_in,
                              void* d_out, int out_size, void* d_ws, size_t ws_size,
                              hipStream_t stream) {
    const float* x     = (const float*)d_in[0];
    const float* W1    = (const float*)d_in[1];
    const float* b1    = (const float*)d_in[2];
    const float* W2    = (const float*)d_in[3];
    const float* b2    = (const float*)d_in[4];
    const float* gamma = (const float*)d_in[5];
    const float* beta  = (const float*)d_in[6];
    float* out = (float*)d_out;

    char* ws = (char*)d_ws;
    _Float16* xh  = (_Float16*)(ws);                        //  67,108,864 B
    _Float16* xl  = (_Float16*)(ws + 67108864);             //  67,108,864 B
    _Float16* whp = (_Float16*)(ws + 134217728);            //   8,388,608 B
    _Float16* wlp = (_Float16*)(ws + 142606336);            //   8,388,608 B
    _Float16* w2q = (_Float16*)(ws + 150994944);            //   1,048,576 B
    float*    part = (float*)  (ws + 152043520);            //  67,108,864 B
    float*    lg   = (float*)  (ws + 219152384);            //   4,194,304 B
    float*    sums = (float*)  (ws + 223346688);            //         256 B

    hipMemsetAsync(sums, 0, NE * sizeof(float), stream);
    k_tw1  <<<4096,    256, 0, stream>>>(W1, whp, wlp);
    k_w2q  <<<64,      256, 0, stream>>>(W2, w2q);
    k_ln   <<<MM,      256, 0, stream>>>(x, gamma, beta, xh, xl);
    k_gemm <<<2048,    256, 0, stream>>>(xh, xl, whp, wlp, w2q, b1, part);
    k_red  <<<4096,    256, 0, stream>>>(part, lg);
    k_final<<<MM/256,  256, 0, stream>>>(lg, b2, out, sums);
    k_aux  <<<1,       64,  0, stream>>>(sums, out);
}